// Round 2
// baseline (186.087 us; speedup 1.0000x reference)
//
#include <hip/hip_runtime.h>

#define N 2048
#define NTHREADS 256
#define ELEMS (N / NTHREADS)   // 8
#define HEIGHT 0.1f
#define PROM 0.05f
#define MINDIST 10             // suppress |i-j| < 10, i.e. +-9

__global__ __launch_bounds__(NTHREADS)
void peak_kernel(const float* __restrict__ x, float* __restrict__ out) {
    __shared__ float xs[N];
    __shared__ unsigned char state[N];  // 0=dead/removed, 1=undecided, 2=kept
    __shared__ unsigned char nk[N];     // newly kept this round
    __shared__ float bmin[64], bmax[64];
    __shared__ float wmin[4], wmax[4];

    const int row = blockIdx.x;
    const int tid = threadIdx.x;
    const float* xr = x + row * N;
    const int base = tid * ELEMS;

    // ---- 1. load + exact min/max reduce + normalize ----
    float vals[ELEMS];
    float lmin = 3.4e38f, lmax = -3.4e38f;
    #pragma unroll
    for (int e = 0; e < ELEMS; ++e) {
        float v = xr[base + e];
        vals[e] = v;
        lmin = fminf(lmin, v);
        lmax = fmaxf(lmax, v);
    }
    #pragma unroll
    for (int off = 32; off > 0; off >>= 1) {
        lmin = fminf(lmin, __shfl_xor(lmin, off, 64));
        lmax = fmaxf(lmax, __shfl_xor(lmax, off, 64));
    }
    const int wave = tid >> 6;
    const int lane = tid & 63;
    if (lane == 0) { wmin[wave] = lmin; wmax[wave] = lmax; }
    __syncthreads();
    const float xmin = fminf(fminf(wmin[0], wmin[1]), fminf(wmin[2], wmin[3]));
    const float xmax = fmaxf(fmaxf(wmax[0], wmax[1]), fmaxf(wmax[2], wmax[3]));
    const float denom = (xmax - xmin) + 1e-5f;
    #pragma unroll
    for (int e = 0; e < ELEMS; ++e) {
        // IEEE f32 division, exactly as the reference (no rcp-mul!)
        xs[base + e] = (vals[e] - xmin) / denom;
        nk[base + e] = 0;
    }
    __syncthreads();

    // ---- 2. candidates: strict local max & height; 32-wide block summaries ----
    #pragma unroll
    for (int e = 0; e < ELEMS; ++e) {
        int i = base + e;
        unsigned char st = 0;
        if (i >= 1 && i <= N - 2) {
            float v = xs[i];
            if (v > xs[i - 1] && v > xs[i + 1] && v >= HEIGHT) st = 1;
        }
        state[i] = st;
    }
    if (tid < 64) {
        float bm = 3.4e38f, bM = -3.4e38f;
        const int s = tid << 5;
        for (int j = 0; j < 32; ++j) {
            float v = xs[s + j];
            bm = fminf(bm, v);
            bM = fmaxf(bM, v);
        }
        bmin[tid] = bm; bmax[tid] = bM;
    }
    __syncthreads();

    // ---- 3. distance suppression: iterated local-winner selection.
    // Equivalent to scipy's highest-first greedy (priority: value desc,
    // index asc). Each round: (A) undecided candidate wins if it beats
    // every undecided candidate within +-9; (B) winners -> kept, their
    // undecided neighbors -> removed. Converges in O(log n) rounds exp.
    for (int round = 0; round < 1024; ++round) {
        #pragma unroll
        for (int e = 0; e < ELEMS; ++e) {
            int i = base + e;
            if (state[i] == 1) {
                float v = xs[i];
                bool win = true;
                int lo = i - (MINDIST - 1); if (lo < 0) lo = 0;
                int hi = i + (MINDIST - 1); if (hi > N - 1) hi = N - 1;
                for (int j = lo; j <= hi; ++j) {
                    if (j == i || state[j] != 1) continue;
                    float u = xs[j];
                    if (u > v || (u == v && j < i)) { win = false; break; }
                }
                nk[i] = win ? 1 : 0;
            }
        }
        __syncthreads();   // publish nk
        int undec = 0;
        #pragma unroll
        for (int e = 0; e < ELEMS; ++e) {
            int i = base + e;
            if (state[i] == 1) {
                if (nk[i]) state[i] = 2;
                else {
                    bool rem = false;
                    int lo = i - (MINDIST - 1); if (lo < 0) lo = 0;
                    int hi = i + (MINDIST - 1); if (hi > N - 1) hi = N - 1;
                    for (int j = lo; j <= hi; ++j) {
                        if (j != i && nk[j]) { rem = true; break; }
                    }
                    if (rem) state[i] = 0; else undec = 1;
                }
            }
        }
        if (__syncthreads_count(undec) == 0) break;  // barrier + race-free term
    }

    // ---- 4. prominence for kept peaks + write output ----
    float* outr = out + row * N;
    for (int idx = tid; idx < N; idx += NTHREADS) {
        float r = 0.0f;
        if (state[idx] == 2) {
            float v = xs[idx];
            const int blk = idx >> 5;
            const int bs = blk << 5;
            // left: min over (L, idx], L = last j<idx with xs[j] > v
            float m = v;
            int j2 = idx - 1;
            bool stopped = false;
            for (; j2 >= bs; --j2) {
                float xv = xs[j2];
                if (xv > v) { stopped = true; break; }
                m = fminf(m, xv);
            }
            if (!stopped) {
                for (int b = blk - 1; b >= 0; --b) {
                    if (bmax[b] > v) {
                        for (j2 = (b << 5) + 31; ; --j2) {
                            float xv = xs[j2];
                            if (xv > v) break;
                            m = fminf(m, xv);
                        }
                        break;
                    } else {
                        m = fminf(m, bmin[b]);
                    }
                }
            }
            const float lmin2 = m;
            // right: min over [idx, R), R = first j>idx with xs[j] > v
            m = v;
            stopped = false;
            const int be = bs + 31;
            j2 = idx + 1;
            for (; j2 <= be; ++j2) {
                float xv = xs[j2];
                if (xv > v) { stopped = true; break; }
                m = fminf(m, xv);
            }
            if (!stopped) {
                for (int b = blk + 1; b < 64; ++b) {
                    if (bmax[b] > v) {
                        for (j2 = (b << 5); ; ++j2) {
                            float xv = xs[j2];
                            if (xv > v) break;
                            m = fminf(m, xv);
                        }
                        break;
                    } else {
                        m = fminf(m, bmin[b]);
                    }
                }
            }
            const float rmin2 = m;
            const float prom = v - fmaxf(lmin2, rmin2);
            r = (prom >= PROM) ? 1.0f : 0.0f;
        }
        outr[idx] = r;
    }
}

extern "C" void kernel_launch(void* const* d_in, const int* in_sizes, int n_in,
                              void* d_out, int out_size, void* d_ws, size_t ws_size,
                              hipStream_t stream) {
    const float* x = (const float*)d_in[0];
    float* outp = (float*)d_out;
    const int rows = in_sizes[0] / N;
    peak_kernel<<<rows, NTHREADS, 0, stream>>>(x, outp);
}

// Round 4
// 61.446 us; speedup vs baseline: 3.0285x; 3.0285x over previous
//
#include <hip/hip_runtime.h>

#define N 2048
#define NT 256
#define EL 8            // elements per thread
#define HEIGHTF 0.1f
#define PROMF 0.05f
#define MD1 9           // MINDIST-1: suppress |i-j| <= 9
#define LVLS 6          // sparse-table levels: windows 2,4,8,16,32,64

__global__ __launch_bounds__(NT)
void peak_kernel(const float* __restrict__ x, float* __restrict__ out) {
    __shared__ float xs[N];
    __shared__ float act[12 + N + 24];        // padded: 12 left guards, 24 right
    __shared__ unsigned char nkb[2 + NT + 3]; // padded winner bytes (1 per thread)
    __shared__ float TMX[LVLS][N];            // TMX[k][i] = max xs[i, min(i+2^(k+1), N))
    __shared__ float TMN[LVLS][N];
    __shared__ float wred[8];

    const int row = blockIdx.x;
    const int t = threadIdx.x;
    const int base = t * EL;
    const float* xr = x + row * (size_t)N;

    // ---- 1. load + exact min/max + normalize (IEEE div, matches reference) ----
    float4 Ld0 = ((const float4*)(xr + base))[0];
    float4 Ld1 = ((const float4*)(xr + base))[1];
    float v0[EL] = {Ld0.x, Ld0.y, Ld0.z, Ld0.w, Ld1.x, Ld1.y, Ld1.z, Ld1.w};
    float mn = v0[0], mx = v0[0];
    #pragma unroll
    for (int e = 1; e < EL; ++e) { mn = fminf(mn, v0[e]); mx = fmaxf(mx, v0[e]); }
    #pragma unroll
    for (int off = 32; off > 0; off >>= 1) {
        mn = fminf(mn, __shfl_xor(mn, off, 64));
        mx = fmaxf(mx, __shfl_xor(mx, off, 64));
    }
    const int wv = t >> 6, ln = t & 63;
    if (ln == 0) { wred[wv] = mn; wred[4 + wv] = mx; }
    // guards (written once, before first use, covered by barriers below)
    if (t == 0) { nkb[0] = 0; nkb[1] = 0; nkb[2+NT] = 0; nkb[2+NT+1] = 0; nkb[2+NT+2] = 0; }
    if (t < 12) act[t] = -1e30f;
    if (t < 24) act[12 + N + t] = -1e30f;
    __syncthreads();
    const float xmin = fminf(fminf(wred[0], wred[1]), fminf(wred[2], wred[3]));
    const float xmax = fmaxf(fmaxf(wred[4], wred[5]), fmaxf(wred[6], wred[7]));
    const float den = (xmax - xmin) + 1e-5f;
    float vn[EL];
    #pragma unroll
    for (int e = 0; e < EL; ++e) {
        vn[e] = (v0[e] - xmin) / den;   // exact IEEE f32 division
        xs[base + e] = vn[e];
    }
    __syncthreads();

    // ---- 2. candidates (strict local max & height); act = cand ? v : -inf ----
    unsigned int undec = 0, kept = 0;
    #pragma unroll
    for (int e = 0; e < EL; ++e) {
        int i = base + e;
        float v = vn[e];
        float lf = (e == 0) ? ((i >= 1) ? xs[i-1] : 3e38f) : vn[e-1];
        float rt = (e == EL-1) ? ((i+1 < N) ? xs[i+1] : 3e38f) : vn[e+1];
        bool c = (i >= 1) && (i <= N-2) && (v > lf) && (v > rt) && (v >= HEIGHTF);
        if (c) undec |= (1u << e);
        act[12 + i] = c ? v : -1e30f;
    }
    __syncthreads();

    // ---- 3. iterated local-winner suppression (== scipy highest-first greedy;
    //          priority: value desc, index asc). All window reads are bulk
    //          independent LDS loads; winner flags are thread-owned bytes. ----
    unsigned char* nkp = nkb + 2;
    float* actp = act + 12;
    for (int round = 0; round < 4096; ++round) {
        unsigned int winb = 0;
        if (undec) {
            // act neighborhood [base-12, base+20): 8 independent b128 loads
            float a[32];
            const float4* wp = (const float4*)(act + base);  // act[] is +12-offset
            #pragma unroll
            for (int q = 0; q < 8; ++q) {
                float4 w = wp[q];
                a[4*q+0] = w.x; a[4*q+1] = w.y; a[4*q+2] = w.z; a[4*q+3] = w.w;
            }
            #pragma unroll
            for (int e = 0; e < EL; ++e) {
                if (undec & (1u << e)) {
                    float v = vn[e];
                    float wl = -1e30f, wr = -1e30f;
                    #pragma unroll
                    for (int d = 0; d < MD1; ++d) wl = fmaxf(wl, a[e + 3 + d]);   // [i-9, i-1]
                    #pragma unroll
                    for (int d = 0; d < MD1; ++d) wr = fmaxf(wr, a[e + 13 + d]);  // [i+1, i+9]
                    // left tie (j<i) beats i -> need strict; right tie loses -> <=
                    if (wl < v && wr <= v) winb |= (1u << e);
                }
            }
        }
        nkp[t] = (unsigned char)winb;   // always write (clears stale winners)
        __syncthreads();
        if (undec) {
            unsigned long long W = 0;   // 40-bit winner window, positions [base-16, base+24)
            #pragma unroll
            for (int q = 0; q < 5; ++q)
                W |= ((unsigned long long)nkp[t - 2 + q]) << (8 * q);
            #pragma unroll
            for (int e = 0; e < EL; ++e) {
                if (undec & (1u << e)) {
                    unsigned long long w19 = (W >> (e + 7)) & 0x7FFFFULL; // bits for [i-9, i+9]
                    if ((w19 >> MD1) & 1ULL) {            // self is winner
                        kept |= (1u << e);
                        undec &= ~(1u << e);
                        actp[base + e] = -1e30f;
                    } else if (w19 & ~(1ULL << MD1)) {    // suppressed by a winner
                        undec &= ~(1u << e);
                        actp[base + e] = -1e30f;
                    }
                }
            }
        }
        if (__syncthreads_count(undec != 0) == 0) break;
    }

    // ---- 4. sparse min/max tables (suffix-clamped), windows 2..64 ----
    #pragma unroll
    for (int e = 0; e < EL; ++e) {
        int i = base + e;
        float nbx, nbn;
        if (e < EL-1) { nbx = vn[e+1]; nbn = vn[e+1]; }
        else if (i + 1 < N) { float u = xs[i+1]; nbx = u; nbn = u; }
        else { nbx = -3e38f; nbn = 3e38f; }
        TMX[0][i] = fmaxf(vn[e], nbx);
        TMN[0][i] = fminf(vn[e], nbn);
    }
    __syncthreads();
    for (int Lv = 1; Lv < LVLS; ++Lv) {
        int h = 1 << Lv;
        #pragma unroll
        for (int e = 0; e < EL; ++e) {
            int i = base + e;
            float ax = TMX[Lv-1][i], an = TMN[Lv-1][i];
            float bx = (i + h < N) ? TMX[Lv-1][i+h] : -3e38f;
            float bn = (i + h < N) ? TMN[Lv-1][i+h] : 3e38f;
            TMX[Lv][i] = fmaxf(ax, bx);
            TMN[Lv][i] = fminf(an, bn);
        }
        __syncthreads();
    }

    // ---- 5. prominence for kept peaks via table-granular walks ----
    float res[EL];
    #pragma unroll
    for (int e = 0; e < EL; ++e) res[e] = 0.0f;

    #pragma unroll
    for (int e = 0; e < EL; ++e) {
        if (kept & (1u << e)) {
            const int i = base + e;
            const float v = vn[e];
            // left base: min over (L, i], L = last j<i with xs[j] > v (or -1)
            float m = v;
            int p = i - 1;
            while (p >= 0) {
                int len = p + 1;
                int k = (len >= 64) ? LVLS : (31 - __clz(len));
                int s = p + 1 - (1 << k);                 // window [s, p]
                float wmx = (k == 0) ? xs[s] : TMX[k-1][s];
                if (wmx > v) {
                    while (k > 0) {                        // descend to last-greater
                        int half = 1 << (k - 1);
                        int rs = s + half;                 // right half [rs, rs+half)
                        float rm = (k == 1) ? xs[rs] : TMX[k-2][rs];
                        if (rm > v) s = rs;
                        else m = fminf(m, (k == 1) ? xs[rs] : TMN[k-2][rs]);
                        --k;
                    }
                    break;                                 // L = s (excluded)
                } else {
                    m = fminf(m, (k == 0) ? xs[s] : TMN[k-1][s]);
                    p = s - 1;
                }
            }
            const float lmin = m;
            // right base: min over [i, R), R = first j>i with xs[j] > v (or N)
            m = v;
            p = i + 1;
            while (p < N) {
                int len = N - p;
                int k = (len >= 64) ? LVLS : (31 - __clz(len));
                float wmx = (k == 0) ? xs[p] : TMX[k-1][p]; // window [p, p+2^k)
                if (wmx > v) {
                    while (k > 0) {                         // descend to first-greater
                        int half = 1 << (k - 1);
                        float lm = (k == 1) ? xs[p] : TMX[k-2][p]; // left half [p, p+half)
                        if (!(lm > v)) {
                            m = fminf(m, (k == 1) ? xs[p] : TMN[k-2][p]);
                            p += half;
                        }
                        --k;
                    }
                    break;                                  // R = p (excluded)
                } else {
                    m = fminf(m, (k == 0) ? xs[p] : TMN[k-1][p]);
                    p += 1 << k;
                }
            }
            const float rmin = m;
            if (v - fmaxf(lmin, rmin) >= PROMF) res[e] = 1.0f;
        }
    }

    float* outr = out + row * (size_t)N + base;
    ((float4*)outr)[0] = make_float4(res[0], res[1], res[2], res[3]);
    ((float4*)outr)[1] = make_float4(res[4], res[5], res[6], res[7]);
}

extern "C" void kernel_launch(void* const* d_in, const int* in_sizes, int n_in,
                              void* d_out, int out_size, void* d_ws, size_t ws_size,
                              hipStream_t stream) {
    const float* x = (const float*)d_in[0];
    float* outp = (float*)d_out;
    const int rows = in_sizes[0] / N;
    peak_kernel<<<rows, NT, 0, stream>>>(x, outp);
}

// Round 5
// 49.647 us; speedup vs baseline: 3.7482x; 1.2376x over previous
//
#include <hip/hip_runtime.h>

#define N 2048
#define NT 256
#define EL 8            // elements per thread
#define HEIGHTF 0.1f
#define PROMF 0.05f
#define MD1 9           // MINDIST-1: suppress |i-j| <= 9
#define LVLS 7          // sparse-table levels: windows 2,4,8,16,32,64,128
#define ACT_G 20        // left guard floats in padded act
#define ACT_SZ 3136     // 20 guard + 256*12 + right guard

__global__ __launch_bounds__(NT)
void peak_kernel(const float* __restrict__ x, float* __restrict__ out) {
    __shared__ float xs[N];
    __shared__ float act[ACT_SZ];             // padded: elem i -> ACT_G + i + (i>>3)*4
    __shared__ unsigned char nkb[2 + NT + 3]; // padded winner bytes (1 per thread)
    __shared__ float TMX[LVLS][N];            // TMX[k][i] = max xs[i, min(i+2^(k+1), N))
    __shared__ float TMN[LVLS][N];
    __shared__ float wred[8];
    __shared__ int cont[2];

    const int row = blockIdx.x;
    const int t = threadIdx.x;
    const int base = t * EL;
    const int abase = ACT_G + t * 12;         // phys float index of elem `base`
    const float* xr = x + row * (size_t)N;

    // ---- 1. load + exact min/max + normalize (IEEE div, matches reference) ----
    float4 Ld0 = ((const float4*)(xr + base))[0];
    float4 Ld1 = ((const float4*)(xr + base))[1];
    float v0[EL] = {Ld0.x, Ld0.y, Ld0.z, Ld0.w, Ld1.x, Ld1.y, Ld1.z, Ld1.w};
    float mn = v0[0], mx = v0[0];
    #pragma unroll
    for (int e = 1; e < EL; ++e) { mn = fminf(mn, v0[e]); mx = fmaxf(mx, v0[e]); }
    #pragma unroll
    for (int off = 32; off > 0; off >>= 1) {
        mn = fminf(mn, __shfl_xor(mn, off, 64));
        mx = fmaxf(mx, __shfl_xor(mx, off, 64));
    }
    const int wv = t >> 6, ln = t & 63;
    if (ln == 0) { wred[wv] = mn; wred[4 + wv] = mx; }
    // guards (written once, covered by the barrier below)
    if (t == 0) {
        nkb[0] = 0; nkb[1] = 0; nkb[2+NT] = 0; nkb[2+NT+1] = 0; nkb[2+NT+2] = 0;
        cont[0] = 0;
    }
    if (t < ACT_G) act[t] = -1e30f;           // left guard phys [0, 20)
    if (t < 48) act[3088 + t] = -1e30f;       // right guard phys [3088, 3136)
    __syncthreads();
    const float xmin = fminf(fminf(wred[0], wred[1]), fminf(wred[2], wred[3]));
    const float xmax = fmaxf(fmaxf(wred[4], wred[5]), fmaxf(wred[6], wred[7]));
    const float den = (xmax - xmin) + 1e-5f;
    float vn[EL];
    #pragma unroll
    for (int e = 0; e < EL; ++e) {
        vn[e] = (v0[e] - xmin) / den;   // exact IEEE f32 division
        xs[base + e] = vn[e];
    }
    __syncthreads();

    // ---- 2. candidates (strict local max & height); act = cand ? v : -inf ----
    unsigned int undec = 0, kept = 0;
    #pragma unroll
    for (int e = 0; e < EL; ++e) {
        int i = base + e;
        float v = vn[e];
        float lf = (e == 0) ? ((i >= 1) ? xs[i-1] : 3e38f) : vn[e-1];
        float rt = (e == EL-1) ? ((i+1 < N) ? xs[i+1] : 3e38f) : vn[e+1];
        bool c = (i >= 1) && (i <= N-2) && (v > lf) && (v > rt) && (v >= HEIGHTF);
        if (c) undec |= (1u << e);
        act[abase + e] = c ? v : -1e30f;
    }
    __syncthreads();

    // ---- 3. iterated local-winner suppression (== scipy highest-first greedy;
    //          priority: value desc, index asc). Padded act layout: thread base
    //          stride 12 floats -> window float4 reads spread all 8 bank groups. ----
    unsigned char* nkp = nkb + 2;
    for (int round = 0; round < 2048; ++round) {
        unsigned int winb = 0;
        if (undec) {
            // window elems [base-12, base+20) via 8 aligned float4 reads
            const float* ab = act + abase;
            float4 r0 = *(const float4*)(ab - 20);   // elems base-12..base-9
            float4 r1 = *(const float4*)(ab - 12);   // elems base-8..base-5
            float4 r2 = *(const float4*)(ab - 8);    // elems base-4..base-1
            float4 r3 = *(const float4*)(ab + 0);    // elems base+0..base+3
            float4 r4 = *(const float4*)(ab + 4);    // elems base+4..base+7
            float4 r5 = *(const float4*)(ab + 12);   // elems base+8..base+11
            float4 r6 = *(const float4*)(ab + 16);   // elems base+12..base+15
            float4 r7 = *(const float4*)(ab + 24);   // elems base+16..base+19
            float a[32] = {r0.x,r0.y,r0.z,r0.w, r1.x,r1.y,r1.z,r1.w,
                           r2.x,r2.y,r2.z,r2.w, r3.x,r3.y,r3.z,r3.w,
                           r4.x,r4.y,r4.z,r4.w, r5.x,r5.y,r5.z,r5.w,
                           r6.x,r6.y,r6.z,r6.w, r7.x,r7.y,r7.z,r7.w};
            #pragma unroll
            for (int e = 0; e < EL; ++e) {
                if (undec & (1u << e)) {
                    float v = vn[e];
                    float wl = -1e30f, wr = -1e30f;
                    #pragma unroll
                    for (int d = 0; d < MD1; ++d) wl = fmaxf(wl, a[e + 3 + d]);   // [i-9, i-1]
                    #pragma unroll
                    for (int d = 0; d < MD1; ++d) wr = fmaxf(wr, a[e + 13 + d]);  // [i+1, i+9]
                    // left tie (j<i) beats i -> need strict; right tie loses -> <=
                    if (wl < v && wr <= v) winb |= (1u << e);
                }
            }
        }
        nkp[t] = (unsigned char)winb;   // always write (clears stale winners)
        __syncthreads();
        if (undec) {
            unsigned long long W = 0;   // 40-bit winner window, positions [base-16, base+24)
            #pragma unroll
            for (int q = 0; q < 5; ++q)
                W |= ((unsigned long long)nkp[t - 2 + q]) << (8 * q);
            #pragma unroll
            for (int e = 0; e < EL; ++e) {
                if (undec & (1u << e)) {
                    unsigned long long w19 = (W >> (e + 7)) & 0x7FFFFULL; // bits for [i-9, i+9]
                    if ((w19 >> MD1) & 1ULL) {            // self is winner
                        kept |= (1u << e);
                        undec &= ~(1u << e);
                        act[abase + e] = -1e30f;
                    } else if (w19 & ~(1ULL << MD1)) {    // suppressed by a winner
                        undec &= ~(1u << e);
                        act[abase + e] = -1e30f;
                    }
                }
            }
        }
        // ping-pong continuation flag (replaces __syncthreads_count)
        if (t == 0) cont[(round + 1) & 1] = 0;
        if (undec) cont[round & 1] = 1;   // multi-writer same value: benign
        __syncthreads();
        if (cont[round & 1] == 0) break;  // uniform broadcast read
    }

    // ---- 4. sparse min/max tables, stride-NT distribution + register carry
    //          (lane-consecutive LDS access = conflict-free) ----
    float cx[EL], cn[EL];
    #pragma unroll
    for (int j = 0; j < EL; ++j) {
        int i = t + j * NT;
        float a0 = xs[i];
        bool inb = (i + 1 < N);
        float nb = inb ? xs[i + 1] : 0.0f;
        cx[j] = fmaxf(a0, inb ? nb : -3e38f);
        cn[j] = fminf(a0, inb ? nb : 3e38f);
        TMX[0][i] = cx[j];
        TMN[0][i] = cn[j];
    }
    __syncthreads();
    for (int Lv = 1; Lv < LVLS; ++Lv) {
        int h = 1 << Lv;
        #pragma unroll
        for (int j = 0; j < EL; ++j) {
            int i = t + j * NT;
            bool inb = (i + h < N);
            float bx = inb ? TMX[Lv-1][i+h] : -3e38f;
            float bn = inb ? TMN[Lv-1][i+h] : 3e38f;
            cx[j] = fmaxf(cx[j], bx);
            cn[j] = fminf(cn[j], bn);
            TMX[Lv][i] = cx[j];
            TMN[Lv][i] = cn[j];
        }
        __syncthreads();
    }

    // ---- 5. prominence for kept peaks via table-granular walks ----
    float res[EL];
    #pragma unroll
    for (int e = 0; e < EL; ++e) res[e] = 0.0f;

    #pragma unroll
    for (int e = 0; e < EL; ++e) {
        if (kept & (1u << e)) {
            const int i = base + e;
            const float v = vn[e];
            // left base: min over (L, i], L = last j<i with xs[j] > v (or -1)
            float m = v;
            int p = i - 1;
            while (p >= 0) {
                int len = p + 1;
                int k = (len >= (1 << LVLS)) ? LVLS : (31 - __clz(len));
                int s = p + 1 - (1 << k);                 // window [s, p]
                float wmx = (k == 0) ? xs[s] : TMX[k-1][s];
                if (wmx > v) {
                    while (k > 0) {                        // descend to last-greater
                        int half = 1 << (k - 1);
                        int rs = s + half;                 // right half [rs, rs+half)
                        float rm = (k == 1) ? xs[rs] : TMX[k-2][rs];
                        if (rm > v) s = rs;
                        else m = fminf(m, (k == 1) ? xs[rs] : TMN[k-2][rs]);
                        --k;
                    }
                    break;                                 // L = s (excluded)
                } else {
                    m = fminf(m, (k == 0) ? xs[s] : TMN[k-1][s]);
                    p = s - 1;
                }
            }
            const float lmin = m;
            // right base: min over [i, R), R = first j>i with xs[j] > v (or N)
            m = v;
            p = i + 1;
            while (p < N) {
                int len = N - p;
                int k = (len >= (1 << LVLS)) ? LVLS : (31 - __clz(len));
                float wmx = (k == 0) ? xs[p] : TMX[k-1][p]; // window [p, p+2^k)
                if (wmx > v) {
                    while (k > 0) {                         // descend to first-greater
                        int half = 1 << (k - 1);
                        float lm = (k == 1) ? xs[p] : TMX[k-2][p]; // left half [p, p+half)
                        if (!(lm > v)) {
                            m = fminf(m, (k == 1) ? xs[p] : TMN[k-2][p]);
                            p += half;
                        }
                        --k;
                    }
                    break;                                  // R = p (excluded)
                } else {
                    m = fminf(m, (k == 0) ? xs[p] : TMN[k-1][p]);
                    p += 1 << k;
                }
            }
            const float rmin = m;
            if (v - fmaxf(lmin, rmin) >= PROMF) res[e] = 1.0f;
        }
    }

    float* outr = out + row * (size_t)N + base;
    ((float4*)outr)[0] = make_float4(res[0], res[1], res[2], res[3]);
    ((float4*)outr)[1] = make_float4(res[4], res[5], res[6], res[7]);
}

extern "C" void kernel_launch(void* const* d_in, const int* in_sizes, int n_in,
                              void* d_out, int out_size, void* d_ws, size_t ws_size,
                              hipStream_t stream) {
    const float* x = (const float*)d_in[0];
    float* outp = (float*)d_out;
    const int rows = in_sizes[0] / N;
    peak_kernel<<<rows, NT, 0, stream>>>(x, outp);
}

// Round 6
// 26.190 us; speedup vs baseline: 7.1052x; 1.8956x over previous
//
#include <hip/hip_runtime.h>

#define N 2048
#define NT 256
#define EL 8            // elements per thread
#define HEIGHTF 0.1f
#define PROMF 0.05f
#define MD1 9           // MINDIST-1: suppress |i-j| <= 9
#define LVLS 8          // sparse-table levels: windows 2,4,...,256
#define ACT_G 20        // left guard floats in padded act
#define ACT_SZ 3136     // 20 guard + 256*12 + right guard

__global__ __launch_bounds__(NT)
void peak_kernel(const float* __restrict__ x, float* __restrict__ out) {
    __shared__ float xs[N];
    __shared__ float act[ACT_SZ];             // padded: elem i -> ACT_G + i + (i>>3)*4
    __shared__ unsigned int nk32[2 + NT + 3]; // winner masks (u32/thread, guarded)
    __shared__ float TMX[LVLS][N];            // TMX[k][i] = max xs[i, min(i+2^(k+1), N))
    __shared__ float TMN[LVLS][N];
    __shared__ float wred[8];
    __shared__ int cont[2];
    __shared__ int kcnt;
    __shared__ unsigned short klist[NT];      // kept-peak positions (<=205)
    __shared__ unsigned char keepres[N];

    const int row = blockIdx.x;
    const int t = threadIdx.x;
    const int base = t * EL;
    const int abase = ACT_G + t * 12;         // phys float index of elem `base`
    const float* xr = x + row * (size_t)N;

    // ---- 1. load + exact min/max + normalize (IEEE div, matches reference) ----
    float4 Ld0 = ((const float4*)(xr + base))[0];
    float4 Ld1 = ((const float4*)(xr + base))[1];
    float v0[EL] = {Ld0.x, Ld0.y, Ld0.z, Ld0.w, Ld1.x, Ld1.y, Ld1.z, Ld1.w};
    float mn = v0[0], mx = v0[0];
    #pragma unroll
    for (int e = 1; e < EL; ++e) { mn = fminf(mn, v0[e]); mx = fmaxf(mx, v0[e]); }
    #pragma unroll
    for (int off = 32; off > 0; off >>= 1) {
        mn = fminf(mn, __shfl_xor(mn, off, 64));
        mx = fmaxf(mx, __shfl_xor(mx, off, 64));
    }
    const int wv = t >> 6, ln = t & 63;
    if (ln == 0) { wred[wv] = mn; wred[4 + wv] = mx; }
    if (t == 0) {
        nk32[0] = 0; nk32[1] = 0; nk32[2+NT] = 0; nk32[2+NT+1] = 0; nk32[2+NT+2] = 0;
        cont[0] = 0; kcnt = 0;
    }
    if (t < ACT_G) act[t] = -1e30f;           // left guard phys [0, 20)
    if (t < 48) act[3088 + t] = -1e30f;       // right guard phys [3088, 3136)
    __syncthreads();
    const float xmin = fminf(fminf(wred[0], wred[1]), fminf(wred[2], wred[3]));
    const float xmax = fmaxf(fmaxf(wred[4], wred[5]), fmaxf(wred[6], wred[7]));
    const float den = (xmax - xmin) + 1e-5f;
    float vn[EL];
    #pragma unroll
    for (int e = 0; e < EL; ++e) {
        vn[e] = (v0[e] - xmin) / den;   // exact IEEE f32 division
        xs[base + e] = vn[e];
    }
    __syncthreads();

    // ---- 2. candidates (strict local max & height); act = cand ? v : -inf ----
    unsigned int undec = 0, kept = 0;
    #pragma unroll
    for (int e = 0; e < EL; ++e) {
        int i = base + e;
        float v = vn[e];
        float lf = (e == 0) ? ((i >= 1) ? xs[i-1] : 3e38f) : vn[e-1];
        float rt = (e == EL-1) ? ((i+1 < N) ? xs[i+1] : 3e38f) : vn[e+1];
        bool c = (i >= 1) && (i <= N-2) && (v > lf) && (v > rt) && (v >= HEIGHTF);
        if (c) undec |= (1u << e);
        act[abase + e] = c ? v : -1e30f;
    }
    __syncthreads();

    // ---- 3. iterated local-winner suppression (== scipy highest-first greedy;
    //          priority: value desc, index asc). Padded act layout: thread base
    //          stride 12 floats -> window float4 reads spread all 8 bank groups. ----
    unsigned int* nkp = nk32 + 2;
    for (int round = 0; round < 2048; ++round) {
        unsigned int winb = 0;
        if (undec) {
            // window elems [base-12, base+20) via 8 aligned float4 reads
            const float* ab = act + abase;
            float4 r0 = *(const float4*)(ab - 20);   // elems base-12..base-9
            float4 r1 = *(const float4*)(ab - 12);   // elems base-8..base-5
            float4 r2 = *(const float4*)(ab - 8);    // elems base-4..base-1
            float4 r3 = *(const float4*)(ab + 0);    // elems base+0..base+3
            float4 r4 = *(const float4*)(ab + 4);    // elems base+4..base+7
            float4 r5 = *(const float4*)(ab + 12);   // elems base+8..base+11
            float4 r6 = *(const float4*)(ab + 16);   // elems base+12..base+15
            float4 r7 = *(const float4*)(ab + 24);   // elems base+16..base+19
            float a[32] = {r0.x,r0.y,r0.z,r0.w, r1.x,r1.y,r1.z,r1.w,
                           r2.x,r2.y,r2.z,r2.w, r3.x,r3.y,r3.z,r3.w,
                           r4.x,r4.y,r4.z,r4.w, r5.x,r5.y,r5.z,r5.w,
                           r6.x,r6.y,r6.z,r6.w, r7.x,r7.y,r7.z,r7.w};
            #pragma unroll
            for (int e = 0; e < EL; ++e) {
                if (undec & (1u << e)) {
                    float v = vn[e];
                    float wl = -1e30f, wr = -1e30f;
                    #pragma unroll
                    for (int d = 0; d < MD1; ++d) wl = fmaxf(wl, a[e + 3 + d]);   // [i-9, i-1]
                    #pragma unroll
                    for (int d = 0; d < MD1; ++d) wr = fmaxf(wr, a[e + 13 + d]);  // [i+1, i+9]
                    // left tie (j<i) beats i -> need strict; right tie loses -> <=
                    if (wl < v && wr <= v) winb |= (1u << e);
                }
            }
        }
        nkp[t] = winb;   // always write (clears stale winners); u32 = conflict-free
        __syncthreads();
        if (undec) {
            unsigned long long W = 0;   // 40-bit winner window, positions [base-16, base+24)
            #pragma unroll
            for (int q = 0; q < 5; ++q)
                W |= ((unsigned long long)(nkp[t - 2 + q] & 0xFFu)) << (8 * q);
            #pragma unroll
            for (int e = 0; e < EL; ++e) {
                if (undec & (1u << e)) {
                    unsigned long long w19 = (W >> (e + 7)) & 0x7FFFFULL; // bits for [i-9, i+9]
                    if ((w19 >> MD1) & 1ULL) {            // self is winner
                        kept |= (1u << e);
                        undec &= ~(1u << e);
                        act[abase + e] = -1e30f;
                    } else if (w19 & ~(1ULL << MD1)) {    // suppressed by a winner
                        undec &= ~(1u << e);
                        act[abase + e] = -1e30f;
                    }
                }
            }
        }
        // ping-pong continuation flag
        if (t == 0) cont[(round + 1) & 1] = 0;
        if (undec) cont[round & 1] = 1;   // multi-writer same value: benign
        __syncthreads();
        if (cont[round & 1] == 0) break;  // uniform broadcast read
    }

    // ---- 4a. compact kept peaks + clear result map ----
    #pragma unroll
    for (int e = 0; e < EL; ++e) {
        keepres[base + e] = 0;
        if (kept & (1u << e)) {
            int slot = atomicAdd(&kcnt, 1);
            klist[slot] = (unsigned short)(base + e);
        }
    }

    // ---- 4b. sparse min/max tables, stride-NT distribution + register carry ----
    float cx[EL], cn[EL];
    #pragma unroll
    for (int j = 0; j < EL; ++j) {
        int i = t + j * NT;
        float a0 = xs[i];
        bool inb = (i + 1 < N);
        float nb = inb ? xs[i + 1] : 0.0f;
        cx[j] = fmaxf(a0, inb ? nb : -3e38f);
        cn[j] = fminf(a0, inb ? nb : 3e38f);
        TMX[0][i] = cx[j];
        TMN[0][i] = cn[j];
    }
    __syncthreads();   // also publishes klist/kcnt/keepres
    for (int Lv = 1; Lv < LVLS; ++Lv) {
        int h = 1 << Lv;
        #pragma unroll
        for (int j = 0; j < EL; ++j) {
            int i = t + j * NT;
            bool inb = (i + h < N);
            float bx = inb ? TMX[Lv-1][i+h] : -3e38f;
            float bn = inb ? TMN[Lv-1][i+h] : 3e38f;
            cx[j] = fmaxf(cx[j], bx);
            cn[j] = fminf(cn[j], bn);
            TMX[Lv][i] = cx[j];
            TMN[Lv][i] = cn[j];
        }
        __syncthreads();
    }

    // ---- 5. prominence: one kept peak per thread (work-balanced) ----
    if (t < kcnt) {
        const int i = klist[t];
        const float v = xs[i];
        // left base: min over (L, i], L = last j<i with xs[j] > v (or -1)
        float m = v;
        int p = i - 1;
        while (p >= 0) {
            int len = p + 1;
            int k = (len >= (1 << LVLS)) ? LVLS : (31 - __clz(len));
            int s = p + 1 - (1 << k);                 // window [s, p]
            float wmx = (k == 0) ? xs[s] : TMX[k-1][s];
            if (wmx > v) {
                while (k > 0) {                        // descend to last-greater
                    int half = 1 << (k - 1);
                    int rs = s + half;                 // right half [rs, rs+half)
                    float rm = (k == 1) ? xs[rs] : TMX[k-2][rs];
                    if (rm > v) s = rs;
                    else m = fminf(m, (k == 1) ? xs[rs] : TMN[k-2][rs]);
                    --k;
                }
                break;                                 // L = s (excluded)
            } else {
                m = fminf(m, (k == 0) ? xs[s] : TMN[k-1][s]);
                p = s - 1;
            }
        }
        const float lmin = m;
        // right base: min over [i, R), R = first j>i with xs[j] > v (or N)
        m = v;
        p = i + 1;
        while (p < N) {
            int len = N - p;
            int k = (len >= (1 << LVLS)) ? LVLS : (31 - __clz(len));
            float wmx = (k == 0) ? xs[p] : TMX[k-1][p]; // window [p, p+2^k)
            if (wmx > v) {
                while (k > 0) {                         // descend to first-greater
                    int half = 1 << (k - 1);
                    float lm = (k == 1) ? xs[p] : TMX[k-2][p]; // left half [p, p+half)
                    if (!(lm > v)) {
                        m = fminf(m, (k == 1) ? xs[p] : TMN[k-2][p]);
                        p += half;
                    }
                    --k;
                }
                break;                                  // R = p (excluded)
            } else {
                m = fminf(m, (k == 0) ? xs[p] : TMN[k-1][p]);
                p += 1 << k;
            }
        }
        const float rmin = m;
        if (v - fmaxf(lmin, rmin) >= PROMF) keepres[i] = 1;
    }
    __syncthreads();

    // ---- 6. output ----
    float res[EL];
    #pragma unroll
    for (int e = 0; e < EL; ++e) res[e] = keepres[base + e] ? 1.0f : 0.0f;
    float* outr = out + row * (size_t)N + base;
    ((float4*)outr)[0] = make_float4(res[0], res[1], res[2], res[3]);
    ((float4*)outr)[1] = make_float4(res[4], res[5], res[6], res[7]);
}

extern "C" void kernel_launch(void* const* d_in, const int* in_sizes, int n_in,
                              void* d_out, int out_size, void* d_ws, size_t ws_size,
                              hipStream_t stream) {
    const float* x = (const float*)d_in[0];
    float* outp = (float*)d_out;
    const int rows = in_sizes[0] / N;
    peak_kernel<<<rows, NT, 0, stream>>>(x, outp);
}

// Round 7
// 24.263 us; speedup vs baseline: 7.6696x; 1.0794x over previous
//
#include <hip/hip_runtime.h>

#define N 2048
#define NT 256
#define EL 8            // elements per thread
#define HEIGHTF 0.1f
#define PROMF 0.05f
#define MD1 9           // MINDIST-1: suppress |i-j| <= 9
#define LVLS 8          // sparse-table levels: windows 2,4,...,256

__global__ __launch_bounds__(NT)
void peak_kernel(const float* __restrict__ x, float* __restrict__ out) {
    __shared__ float xs[N];
    __shared__ float actl[16 + N + 24];       // act with -inf guards (pos p -> actl[16+p])
    __shared__ unsigned int nk32[3 + NT + 3]; // winner words, 3 guard words each side
    __shared__ float TMX[LVLS][N];            // TMX[k][i] = max xs[i, min(i+2^(k+1), N))
    __shared__ float TMN[LVLS][N];
    __shared__ float wred[8];
    __shared__ int cont[2];
    __shared__ int wtot[4];
    __shared__ unsigned short klist[NT];
    __shared__ unsigned char keepres[N];

    const int row = blockIdx.x;
    const int t = threadIdx.x;
    const int base = t * EL;
    const float* xr = x + row * (size_t)N;
    const int wv = t >> 6, ln = t & 63;

    // ---- 1. load + exact min/max + guards ----
    float4 Ld0 = ((const float4*)(xr + base))[0];
    float4 Ld1 = ((const float4*)(xr + base))[1];
    float v0[EL] = {Ld0.x, Ld0.y, Ld0.z, Ld0.w, Ld1.x, Ld1.y, Ld1.z, Ld1.w};
    float mn = v0[0], mx = v0[0];
    #pragma unroll
    for (int e = 1; e < EL; ++e) { mn = fminf(mn, v0[e]); mx = fmaxf(mx, v0[e]); }
    #pragma unroll
    for (int off = 32; off > 0; off >>= 1) {
        mn = fminf(mn, __shfl_xor(mn, off, 64));
        mx = fmaxf(mx, __shfl_xor(mx, off, 64));
    }
    if (ln == 0) { wred[wv] = mn; wred[4 + wv] = mx; }
    if (t == 0) {
        nk32[0] = 0; nk32[1] = 0; nk32[2] = 0;
        nk32[3+NT] = 0; nk32[3+NT+1] = 0; nk32[3+NT+2] = 0;
        cont[0] = 0;
    }
    if (t < 16) actl[t] = -1e30f;             // positions -16..-1
    if (t < 24) actl[16 + N + t] = -1e30f;    // positions N..N+23
    __syncthreads();

    // ---- 2. normalize (exact IEEE f32 division, matches reference) ----
    const float xmin = fminf(fminf(wred[0], wred[1]), fminf(wred[2], wred[3]));
    const float xmax = fmaxf(fmaxf(wred[4], wred[5]), fmaxf(wred[6], wred[7]));
    const float den = (xmax - xmin) + 1e-5f;
    float vn[EL];
    #pragma unroll
    for (int e = 0; e < EL; ++e) {
        vn[e] = (v0[e] - xmin) / den;
        xs[base + e] = vn[e];
    }
    __syncthreads();

    // ---- 3. candidates (strict local max & height) ----
    unsigned int undec = 0, kept = 0;
    #pragma unroll
    for (int e = 0; e < EL; ++e) {
        int i = base + e;
        float v = vn[e];
        float lf = (e == 0) ? ((i >= 1) ? xs[i-1] : 3e38f) : vn[e-1];
        float rt = (e == EL-1) ? ((i+1 < N) ? xs[i+1] : 3e38f) : vn[e+1];
        bool c = (i >= 1) && (i <= N-2) && (v > lf) && (v > rt) && (v >= HEIGHTF);
        if (c) undec |= (1u << e);
        actl[16 + i] = c ? v : -1e30f;
    }
    __syncthreads();

    // ---- 4. gather register act window a[40] = positions [base-16, base+24) ----
    float a[40];
    {
        const float4* ap = (const float4*)(actl + base);  // actl[base] = pos base-16
        #pragma unroll
        for (int q = 0; q < 10; ++q) {
            float4 w = ap[q];
            a[4*q+0] = w.x; a[4*q+1] = w.y; a[4*q+2] = w.z; a[4*q+3] = w.w;
        }
    }

    // win computation macro body (shared-subexpression 9-wide max tree)
    auto compute_wins = [&](unsigned int ud) -> unsigned int {
        float m2v[25], m4v[23], m8v[19];
        #pragma unroll
        for (int s = 0; s < 25; ++s) m2v[s] = fmaxf(a[7+s], a[8+s]);
        #pragma unroll
        for (int s = 0; s < 23; ++s) m4v[s] = fmaxf(m2v[s], m2v[s+2]);
        #pragma unroll
        for (int s = 0; s < 19; ++s) m8v[s] = fmaxf(m4v[s], m4v[s+4]);
        unsigned int wb = 0;
        #pragma unroll
        for (int e = 0; e < EL; ++e) {
            if (ud & (1u << e)) {
                float v = a[16+e];
                float wl = fmaxf(m8v[e], a[15+e]);      // max act [i-9, i-1]
                float wr = fmaxf(m8v[10+e], a[25+e]);   // max act [i+1, i+9]
                // left tie (j<i) beats i -> strict; right tie loses -> <=
                if (wl < v && wr <= v) wb |= (1u << e);
            }
        }
        return wb;
    };

    unsigned int winb = undec ? compute_wins(undec) : 0u;

    // ---- 5. iterated local-winner suppression (== scipy highest-first greedy),
    //          ONE barrier per round; all act state in registers ----
    unsigned int* nkp = nk32 + 3;
    for (int round = 0; round < 2048; ++round) {
        nkp[t] = winb;
        if (t == 0) cont[(round + 1) & 1] = 0;
        if (undec) cont[round & 1] = 1;
        __syncthreads();
        if (cont[round & 1] == 0) break;
        // compose 57-bit winner window V: V bit (s+9) = winner at pos base-16+s
        unsigned long long V = 0;
        #pragma unroll
        for (int q = 0; q < 7; ++q)
            V |= ((unsigned long long)(nkp[t - 3 + q] & 0xFFu)) << (8 * q);
        V <<= 1;
        if (__ballot(V != 0ULL)) {
            // own elem decisions
            #pragma unroll
            for (int e = 0; e < EL; ++e) {
                if (undec & (1u << e)) {
                    unsigned int w19 = (unsigned int)((V >> (16 + e)) & 0x7FFFFULL);
                    if (w19 & (1u << 9)) { kept |= (1u << e); undec &= ~(1u << e); }
                    else if (w19)        { undec &= ~(1u << e); }
                }
            }
            // clear act for every slot within 9 of a winner (incl. winners)
            #pragma unroll
            for (int s = 0; s < 40; ++s) {
                if ((V >> s) & 0x7FFFFULL) a[s] = -1e30f;
            }
        }
        winb = 0;
        if (__ballot(undec != 0)) winb = compute_wins(undec);
    }

    // ---- 6a. level-0 tables + kept-peak prefix (ballot compaction) + clear map ----
    float cx[EL], cn[EL];
    #pragma unroll
    for (int j = 0; j < EL; ++j) {
        int i = t + j * NT;
        float a0 = xs[i];
        bool inb = (i + 1 < N);
        float nb = inb ? xs[i + 1] : 0.0f;
        cx[j] = fmaxf(a0, inb ? nb : -3e38f);
        cn[j] = fminf(a0, inb ? nb : 3e38f);
        TMX[0][i] = cx[j];
        TMN[0][i] = cn[j];
    }
    int myc = __popc(kept);
    int pre = myc;
    #pragma unroll
    for (int off = 1; off < 64; off <<= 1) {
        int up = __shfl_up(pre, off, 64);
        if (ln >= off) pre += up;
    }
    if (ln == 63) wtot[wv] = pre;
    #pragma unroll
    for (int e = 0; e < EL; ++e) keepres[base + e] = 0;
    __syncthreads();

    // ---- 6b. klist scatter + table levels 1..7 ----
    {
        int woff = 0;
        #pragma unroll
        for (int w = 0; w < 4; ++w) woff += (w < wv) ? wtot[w] : 0;
        int slot = woff + pre - myc;
        #pragma unroll
        for (int e = 0; e < EL; ++e)
            if (kept & (1u << e)) klist[slot++] = (unsigned short)(base + e);
    }
    const int ktot = wtot[0] + wtot[1] + wtot[2] + wtot[3];
    for (int Lv = 1; Lv < LVLS; ++Lv) {
        int h = 1 << Lv;
        #pragma unroll
        for (int j = 0; j < EL; ++j) {
            int i = t + j * NT;
            bool inb = (i + h < N);
            float bx = inb ? TMX[Lv-1][i+h] : -3e38f;
            float bn = inb ? TMN[Lv-1][i+h] : 3e38f;
            cx[j] = fmaxf(cx[j], bx);
            cn[j] = fminf(cn[j], bn);
            TMX[Lv][i] = cx[j];
            TMN[Lv][i] = cn[j];
        }
        __syncthreads();
    }

    // ---- 7. prominence: one kept peak per thread (work-balanced) ----
    if (t < ktot) {
        const int i = klist[t];
        const float v = xs[i];
        // left base: min over (L, i], L = last j<i with xs[j] > v (or -1)
        float m = v;
        int p = i - 1;
        while (p >= 0) {
            int len = p + 1;
            int k = (len >= (1 << LVLS)) ? LVLS : (31 - __clz(len));
            int s = p + 1 - (1 << k);                 // window [s, p]
            float wmx = (k == 0) ? xs[s] : TMX[k-1][s];
            if (wmx > v) {
                while (k > 0) {                        // descend to last-greater
                    int half = 1 << (k - 1);
                    int rs = s + half;
                    float rm = (k == 1) ? xs[rs] : TMX[k-2][rs];
                    if (rm > v) s = rs;
                    else m = fminf(m, (k == 1) ? xs[rs] : TMN[k-2][rs]);
                    --k;
                }
                break;
            } else {
                m = fminf(m, (k == 0) ? xs[s] : TMN[k-1][s]);
                p = s - 1;
            }
        }
        const float lmin = m;
        // right base: min over [i, R), R = first j>i with xs[j] > v (or N)
        m = v;
        p = i + 1;
        while (p < N) {
            int len = N - p;
            int k = (len >= (1 << LVLS)) ? LVLS : (31 - __clz(len));
            float wmx = (k == 0) ? xs[p] : TMX[k-1][p];
            if (wmx > v) {
                while (k > 0) {
                    int half = 1 << (k - 1);
                    float lm = (k == 1) ? xs[p] : TMX[k-2][p];
                    if (!(lm > v)) {
                        m = fminf(m, (k == 1) ? xs[p] : TMN[k-2][p]);
                        p += half;
                    }
                    --k;
                }
                break;
            } else {
                m = fminf(m, (k == 0) ? xs[p] : TMN[k-1][p]);
                p += 1 << k;
            }
        }
        const float rmin = m;
        if (v - fmaxf(lmin, rmin) >= PROMF) keepres[i] = 1;
    }
    __syncthreads();

    // ---- 8. output ----
    float res[EL];
    #pragma unroll
    for (int e = 0; e < EL; ++e) res[e] = keepres[base + e] ? 1.0f : 0.0f;
    float* outr = out + row * (size_t)N + base;
    ((float4*)outr)[0] = make_float4(res[0], res[1], res[2], res[3]);
    ((float4*)outr)[1] = make_float4(res[4], res[5], res[6], res[7]);
}

extern "C" void kernel_launch(void* const* d_in, const int* in_sizes, int n_in,
                              void* d_out, int out_size, void* d_ws, size_t ws_size,
                              hipStream_t stream) {
    const float* x = (const float*)d_in[0];
    float* outp = (float*)d_out;
    const int rows = in_sizes[0] / N;
    peak_kernel<<<rows, NT, 0, stream>>>(x, outp);
}